// Round 4
// baseline (571.664 us; speedup 1.0000x reference)
//
#include <hip/hip_runtime.h>
#include <hip/hip_bf16.h>
#include <math.h>

// Problem constants (fixed dataset: n=100, k=5, q=75, d=4096)
#define NQUERY 7500
#define NCLS   100
#define DIM    4096
#define KQ     75
#define KSUP   5
#define RPC    80        // rows per class in x = k+q
#define MPAD   7552      // 118 * 64
#define NPAD   112       // 7 * 16
#define CAPQ   256       // max queries per class list
#define RCAP   2048      // max refine entries
#define EPSF   1e-8f
#define SELEM  845824    // MPAD * NPAD elements per partial slice
#define SLICE_BYTES 3383296u

typedef __attribute__((ext_vector_type(8))) short bf16x8;
typedef __attribute__((ext_vector_type(4))) float f32x4;

__device__ __forceinline__ int xrow_of_query(int j) {
    return (j / KQ) * RPC + KSUP + (j % KQ);
}
__device__ __forceinline__ short bf16t(float x) {       // truncate fp32 -> bf16 bits
    union { float f; unsigned u; } v; v.f = x;
    return (short)(v.u >> 16);
}
__device__ __forceinline__ float bf16hi(float x) {      // fp32 with low mantissa cleared
    union { float f; unsigned u; } v; v.f = x;
    v.u &= 0xFFFF0000u; return v.f;
}

// ---------------- K1a: proto chunk + partial norm2  (grid: NCLS x 4 chunks)
__global__ __launch_bounds__(256) void k_proto1(const float* __restrict__ x,
        float* __restrict__ proto, float* __restrict__ norm2) {
    const int c = blockIdx.x, ch = blockIdx.y, t = threadIdx.x;
    const int i = ch * 1024 + t * 4;
    const float* b0 = x + (size_t)(c * RPC) * DIM;
    f32x4 s = {0.f, 0.f, 0.f, 0.f};
#pragma unroll
    for (int r = 0; r < KSUP; ++r)
        s += *(const f32x4*)(b0 + (size_t)r * DIM + i);
    s = s / 5.0f;
    *(f32x4*)(proto + (size_t)c*DIM + i) = s;
    float ssq = s[0]*s[0] + s[1]*s[1] + s[2]*s[2] + s[3]*s[3];
    for (int o = 32; o; o >>= 1) ssq += __shfl_down(ssq, o);
    if ((t & 63) == 0) atomicAdd(&norm2[c], ssq);
}

// ---------------- K1b: normalize -> Phi/Plo bf16 split, es  (grid: NPAD x 4)
__global__ __launch_bounds__(256) void k_proto2(const float* __restrict__ proto,
        const float* __restrict__ norm2, short* __restrict__ Phi, short* __restrict__ Plo,
        float* __restrict__ es) {
    const int c = blockIdx.x, ch = blockIdx.y, t = threadIdx.x;
    const int i = ch * 1024 + t * 4;
    if (c >= NCLS) {
#pragma unroll
        for (int e = 0; e < 4; ++e) { Phi[(size_t)c*DIM+i+e] = 0; Plo[(size_t)c*DIM+i+e] = 0; }
        return;
    }
    const float tot = norm2[c];
    const float inv = 1.f / fmaxf(sqrtf(tot), EPSF);
    if (ch == 0 && t == 0) es[c] = expf(tot * inv * inv);
    f32x4 pv = *(const f32x4*)(proto + (size_t)c*DIM + i);
#pragma unroll
    for (int e = 0; e < 4; ++e) {
        float pn = pv[e] * inv;
        float hh = bf16hi(pn);
        Phi[(size_t)c*DIM + i + e] = bf16t(pn);
        Plo[(size_t)c*DIM + i + e] = bf16t(pn - hh);
    }
}

// ---------------- K2: GEMM1 partials  Spart[kz][j,c] = q_j . pn_c  (3-term bf16 split)
// grid (118, TNKS), block 256: 4 waves, each 1 m-tile (16 rows) x 7 n-tiles.
// TNKS compile-time -> K-loop fully unrolled -> loads batched (MLP).
template<int TNKS>
__global__ __launch_bounds__(256, 4) void k_gemm1(const float* __restrict__ x,
        const short* __restrict__ Phi, const short* __restrict__ Plo,
        float* __restrict__ Spart, float* __restrict__ nq2) {
    constexpr int kchunk = DIM / TNKS;
    constexpr int nit = kchunk / 32;
    const int bx = blockIdx.x, kz = blockIdx.y;
    const int w = threadIdx.x >> 6, lane = threadIdx.x & 63;
    const int lm = lane & 15, kq = lane >> 4;
    const int m0 = bx * 64 + w * 16;

    const int j = m0 + lm;
    const int jc = j < NQUERY ? j : NQUERY - 1;
    const float* pa = x + (size_t)xrow_of_query(jc) * DIM + kz * kchunk + kq * 8;
    const short* pbh = Phi + (size_t)lm * DIM + kz * kchunk + kq * 8;
    const short* pbl = Plo + (size_t)lm * DIM + kz * kchunk + kq * 8;

    f32x4 acc[7];
#pragma unroll
    for (int nt = 0; nt < 7; ++nt) acc[nt] = (f32x4){0.f,0.f,0.f,0.f};
    float ssq = 0.f;

#pragma unroll 8
    for (int ks = 0; ks < nit; ++ks) {
        const int ko = ks * 32;
        f32x4 f0 = *(const f32x4*)(pa + ko);
        f32x4 f1 = *(const f32x4*)(pa + ko + 4);
        float fv[8] = {f0[0],f0[1],f0[2],f0[3],f1[0],f1[1],f1[2],f1[3]};
        bf16x8 ah, al;
#pragma unroll
        for (int e = 0; e < 8; ++e) {
            float xx = fv[e];
            ssq += xx * xx;
            float hh = bf16hi(xx);
            ah[e] = bf16t(xx);
            al[e] = bf16t(xx - hh);
        }
        bf16x8 bh[7], bl[7];
#pragma unroll
        for (int nt = 0; nt < 7; ++nt) {
            bh[nt] = *(const bf16x8*)(pbh + (size_t)nt * 16 * DIM + ko);
            bl[nt] = *(const bf16x8*)(pbl + (size_t)nt * 16 * DIM + ko);
        }
#pragma unroll
        for (int nt = 0; nt < 7; ++nt) {
            acc[nt] = __builtin_amdgcn_mfma_f32_16x16x32_bf16(ah, bh[nt], acc[nt], 0, 0, 0);
            acc[nt] = __builtin_amdgcn_mfma_f32_16x16x32_bf16(ah, bl[nt], acc[nt], 0, 0, 0);
            acc[nt] = __builtin_amdgcn_mfma_f32_16x16x32_bf16(al, bh[nt], acc[nt], 0, 0, 0);
        }
    }
    // query norm^2: lanes {lm, lm+16, lm+32, lm+48} hold same row
    float s2 = ssq;
    s2 += __shfl_xor(s2, 16);
    s2 += __shfl_xor(s2, 32);
    if (kq == 0 && j < NQUERY) atomicAdd(&nq2[j], s2);

    float* sp = Spart + (size_t)kz * SELEM;
#pragma unroll
    for (int nt = 0; nt < 7; ++nt)
#pragma unroll
        for (int r = 0; r < 4; ++r) {
            int jj = m0 + kq * 4 + r;
            int c = nt * 16 + lm;
            sp[(size_t)jj * NPAD + c] = acc[nt][r];
        }
}

// ---------------- K2b: Sred = sum over kz slices  (grid 826 x 256, f32x4/thread)
__global__ __launch_bounds__(256) void k_reduce1(const float* __restrict__ Spart,
        float* __restrict__ Sred, int nks) {
    const int idx = blockIdx.x * 256 + threadIdx.x;   // < 211456
    const size_t e = (size_t)idx * 4;
    f32x4 s = {0.f, 0.f, 0.f, 0.f};
    for (int kz = 0; kz < nks; ++kz)
        s += *(const f32x4*)(Spart + (size_t)kz * SELEM + e);
    *(f32x4*)(Sred + e) = s;
}

// ---------------- K3: per-query argmax/top2, invq, coef, refine-list
__global__ __launch_bounds__(256) void k_argmax(const float* __restrict__ S,
        const float* __restrict__ nq2, int* __restrict__ label, float* __restrict__ coef,
        float* __restrict__ invq, int* __restrict__ rcnt, int* __restrict__ rlist) {
    const int j = blockIdx.x * 256 + threadIdx.x;
    if (j >= NQUERY) return;
    const float* row = S + (size_t)j * NPAD;
    float m1 = -1e30f, m2 = -1e30f;
    int i1 = 0, i2 = 0;
    for (int c = 0; c < NCLS; ++c) {
        float v = row[c];
        if (v > m1) { m2 = m1; i2 = i1; m1 = v; i1 = c; }
        else if (v > m2) { m2 = v; i2 = c; }
    }
    const float inv = 1.f / fmaxf(sqrtf(nq2[j]), EPSF);
    invq[j] = inv;
    label[j] = i1;
    coef[j] = expf(m1 * inv);
    if ((m1 - m2) * inv < 1e-4f) {
        int p = atomicAdd(rcnt, 1);
        if (p < RCAP) rlist[p] = j | (i1 << 13) | (i2 << 20);
    }
}

// ---------------- K4: fp64 refinement of borderline argmax decisions (1 wave/block)
__global__ __launch_bounds__(64) void k_refine(const float* __restrict__ x,
        const float* __restrict__ S, const float* __restrict__ invq,
        int* __restrict__ label, float* __restrict__ coef,
        const int* __restrict__ rcnt, const int* __restrict__ rlist) {
    const int cnt = min(*rcnt, RCAP);
    const int lane = threadIdx.x;
    for (int e = blockIdx.x; e < cnt; e += gridDim.x) {
        const int pk = rlist[e];
        const int j = pk & 8191, c1 = (pk >> 13) & 127, c2 = (pk >> 20) & 127;
        const float* xq = x + (size_t)xrow_of_query(j) * DIM;
        const int cc[2] = {c1, c2};
        double cosv[2];
#pragma unroll
        for (int s = 0; s < 2; ++s) {
            const float* xb = x + (size_t)(cc[s] * RPC) * DIM;
            double dt = 0.0, pp = 0.0, q2 = 0.0;
            for (int i = lane; i < DIM; i += 64) {
                double p = (double)xb[i] + (double)xb[i + DIM] + (double)xb[i + 2*DIM]
                         + (double)xb[i + 3*DIM] + (double)xb[i + 4*DIM];
                double qv = (double)xq[i];
                dt += p * qv; pp += p * p; q2 += qv * qv;
            }
            for (int o = 32; o; o >>= 1) {
                dt += __shfl_down(dt, o);
                pp += __shfl_down(pp, o);
                q2 += __shfl_down(q2, o);
            }
            cosv[s] = dt / (sqrt(pp) * sqrt(q2));   // /5 on proto cancels in cosine
        }
        if (lane == 0) {
            int win = (cosv[1] > cosv[0] || (cosv[1] == cosv[0] && c2 < c1)) ? c2 : c1;
            if (win != c1) {
                label[j] = win;
                coef[j] = expf(S[(size_t)j * NPAD + win] * invq[j]);
            }
        }
    }
}

// ---------------- K5: build per-class query lists
__global__ __launch_bounds__(256) void k_lists(const int* __restrict__ label,
        int* __restrict__ cls_cnt, int* __restrict__ cls_list) {
    const int j = blockIdx.x * 256 + threadIdx.x;
    if (j >= NQUERY) return;
    const int c = label[j];
    const int p = atomicAdd(&cls_cnt[c], 1);
    if (p < CAPQ) cls_list[c * CAPQ + p] = j;
}

// ---------------- K6: adapted-proto partial scatter sum, plain stores (grid 8 x NCLS x 4)
__global__ __launch_bounds__(128) void k_adapt(const float* __restrict__ x,
        const float* __restrict__ coef, const int* __restrict__ cls_cnt,
        const int* __restrict__ cls_list, float* __restrict__ APpart) {
    const int cx = blockIdx.x, c = blockIdx.y, sl = blockIdx.z;
    const int i0 = cx * 512 + threadIdx.x * 4;
    const int n = min(cls_cnt[c], CAPQ);
    f32x4 acc = {0.f, 0.f, 0.f, 0.f};
    for (int e = sl; e < n; e += 4) {
        const int j = cls_list[c * CAPQ + e];
        const float cf = coef[j];
        const f32x4 v = *(const f32x4*)(x + (size_t)xrow_of_query(j) * DIM + i0);
        acc += v * cf;
    }
    *(f32x4*)(APpart + (size_t)sl * NCLS * DIM + (size_t)c * DIM + i0) = acc;
}

// ---------------- K7a: combine slices + es*proto -> APpart slice0, partial norm2b
__global__ __launch_bounds__(256) void k_ap1(float* __restrict__ APpart,
        const float* __restrict__ proto, const float* __restrict__ es,
        float* __restrict__ norm2b) {
    const int c = blockIdx.x, ch = blockIdx.y, t = threadIdx.x;
    const int i = ch * 1024 + t * 4;
    const float e = es[c];
    f32x4 s = {0.f, 0.f, 0.f, 0.f};
#pragma unroll
    for (int sl = 0; sl < 4; ++sl)
        s += *(const f32x4*)(APpart + (size_t)sl * NCLS * DIM + (size_t)c * DIM + i);
    f32x4 pr = *(const f32x4*)(proto + (size_t)c*DIM + i);
    s += pr * e;
    *(f32x4*)(APpart + (size_t)c*DIM + i) = s;   // combined -> slice 0
    float ssq = s[0]*s[0] + s[1]*s[1] + s[2]*s[2] + s[3]*s[3];
    for (int o = 32; o; o >>= 1) ssq += __shfl_down(ssq, o);
    if ((t & 63) == 0) atomicAdd(&norm2b[c], ssq);
}

// ---------------- K7b: normalize APpart0 -> APhi bf16 (padded rows zero)
__global__ __launch_bounds__(256) void k_ap2(const float* __restrict__ AP0,
        const float* __restrict__ norm2b, short* __restrict__ APhi) {
    const int c = blockIdx.x, ch = blockIdx.y, t = threadIdx.x;
    const int i = ch * 1024 + t * 4;
    if (c >= NCLS) {
#pragma unroll
        for (int e = 0; e < 4; ++e) APhi[(size_t)c*DIM + i + e] = 0;
        return;
    }
    const float inv = 1.f / fmaxf(sqrtf(norm2b[c]), EPSF);
    f32x4 a = *(const f32x4*)(AP0 + (size_t)c*DIM + i);
#pragma unroll
    for (int e = 0; e < 4; ++e) APhi[(size_t)c*DIM + i + e] = bf16t(a[e] * inv);
}

// ---------------- K8: GEMM2 partials  Opart[kz][j,c] = q_j . apn_c  (bf16-hi only)
template<int TNKS>
__global__ __launch_bounds__(256, 4) void k_gemm2(const float* __restrict__ x,
        const short* __restrict__ APhi, float* __restrict__ Opart) {
    constexpr int kchunk = DIM / TNKS;
    constexpr int nit = kchunk / 32;
    const int bx = blockIdx.x, kz = blockIdx.y;
    const int w = threadIdx.x >> 6, lane = threadIdx.x & 63;
    const int lm = lane & 15, kq = lane >> 4;
    const int m0 = bx * 64 + w * 16;

    const int j = m0 + lm;
    const int jc = j < NQUERY ? j : NQUERY - 1;
    const float* pa = x + (size_t)xrow_of_query(jc) * DIM + kz * kchunk + kq * 8;
    const short* pb = APhi + (size_t)lm * DIM + kz * kchunk + kq * 8;

    f32x4 acc[7];
#pragma unroll
    for (int nt = 0; nt < 7; ++nt) acc[nt] = (f32x4){0.f,0.f,0.f,0.f};

#pragma unroll 8
    for (int ks = 0; ks < nit; ++ks) {
        const int ko = ks * 32;
        f32x4 f0 = *(const f32x4*)(pa + ko);
        f32x4 f1 = *(const f32x4*)(pa + ko + 4);
        float fv[8] = {f0[0],f0[1],f0[2],f0[3],f1[0],f1[1],f1[2],f1[3]};
        bf16x8 ah;
#pragma unroll
        for (int e = 0; e < 8; ++e) ah[e] = bf16t(fv[e]);
        bf16x8 bh[7];
#pragma unroll
        for (int nt = 0; nt < 7; ++nt)
            bh[nt] = *(const bf16x8*)(pb + (size_t)nt * 16 * DIM + ko);
#pragma unroll
        for (int nt = 0; nt < 7; ++nt)
            acc[nt] = __builtin_amdgcn_mfma_f32_16x16x32_bf16(ah, bh[nt], acc[nt], 0, 0, 0);
    }
    float* op = Opart + (size_t)kz * SELEM;
#pragma unroll
    for (int nt = 0; nt < 7; ++nt)
#pragma unroll
        for (int r = 0; r < 4; ++r) {
            int jj = m0 + kq * 4 + r;
            int c = nt * 16 + lm;
            op[(size_t)jj * NPAD + c] = acc[nt][r];
        }
}

// ---------------- K8b: out[j,c<100] = tao * invq[j] * sum_kz Opart  (grid 733 x 256)
__global__ __launch_bounds__(256) void k_reduce2(const float* __restrict__ Opart,
        const float* __restrict__ invq, const float* __restrict__ tao,
        float* __restrict__ out, int nks) {
    const int idx = blockIdx.x * 256 + threadIdx.x;   // < 187500
    if (idx >= NQUERY * 25) return;
    const int j = idx / 25, c4 = (idx % 25) * 4;
    const size_t e = (size_t)j * NPAD + c4;
    f32x4 s = {0.f, 0.f, 0.f, 0.f};
    for (int kz = 0; kz < nks; ++kz)
        s += *(const f32x4*)(Opart + (size_t)kz * SELEM + e);
    const float sc = tao[0] * invq[j];
    *(f32x4*)(out + (size_t)j * NCLS + c4) = s * sc;
}

// ---------------- workspace layout (bytes)
#define OFF_NQ2    0u
#define OFF_N2     30208u
#define OFF_N2B    30720u
#define OFF_CCNT   31232u
#define OFF_RCNT   31744u
#define ZERO_BYTES 32768u
#define OFF_SRED   32768u       // 3,383,296
#define OFF_APPART 3416064u     // 4 x 1,638,400
#define OFF_PROTO  9969664u     // 1,638,400
#define OFF_PHI    11608064u    // 917,504
#define OFF_PLO    12525568u    // 917,504
#define OFF_APHI   13443072u    // 917,504
#define OFF_LABEL  14360576u
#define OFF_COEF   14390784u
#define OFF_INVQ   14420992u
#define OFF_RLIST  14451200u
#define OFF_CLIST  14459392u
#define OFF_ES     14561792u
#define OFF_PART   14562304u    // + nks x 3,383,296 (runtime-sized)

extern "C" void kernel_launch(void* const* d_in, const int* in_sizes, int n_in,
                              void* d_out, int out_size, void* d_ws, size_t ws_size,
                              hipStream_t stream) {
    const float* x   = (const float*)d_in[0];
    const float* tao = (const float*)d_in[1];
    char* ws = (char*)d_ws;

    float* nq2     = (float*)(ws + OFF_NQ2);
    float* norm2   = (float*)(ws + OFF_N2);
    float* norm2b  = (float*)(ws + OFF_N2B);
    int*   ccnt    = (int*)  (ws + OFF_CCNT);
    int*   rcnt    = (int*)  (ws + OFF_RCNT);
    float* Sred    = (float*)(ws + OFF_SRED);
    float* APpart  = (float*)(ws + OFF_APPART);
    float* proto   = (float*)(ws + OFF_PROTO);
    short* Phi     = (short*)(ws + OFF_PHI);
    short* Plo     = (short*)(ws + OFF_PLO);
    short* APhi    = (short*)(ws + OFF_APHI);
    int*   label   = (int*)  (ws + OFF_LABEL);
    float* coef    = (float*)(ws + OFF_COEF);
    float* invq    = (float*)(ws + OFF_INVQ);
    int*   rlist   = (int*)  (ws + OFF_RLIST);
    int*   clist   = (int*)  (ws + OFF_CLIST);
    float* es      = (float*)(ws + OFF_ES);
    float* Part    = (float*)(ws + OFF_PART);

    // runtime k-split count from available scratch (pow2, 1..16)
    int nks = 1;
    if (ws_size > (size_t)OFF_PART + SLICE_BYTES) {
        size_t avail = (ws_size - OFF_PART) / SLICE_BYTES;
        nks = avail >= 16 ? 16 : (int)avail;
        while (nks & (nks - 1)) nks &= nks - 1;   // round down to power of two
    }

    hipMemsetAsync(ws, 0, ZERO_BYTES, stream);

    k_proto1 <<<dim3(NCLS, 4), 256, 0, stream>>>(x, proto, norm2);
    k_proto2 <<<dim3(NPAD, 4), 256, 0, stream>>>(proto, norm2, Phi, Plo, es);

    switch (nks) {
        case 16: k_gemm1<16><<<dim3(118, 16), 256, 0, stream>>>(x, Phi, Plo, Part, nq2); break;
        case 8:  k_gemm1<8> <<<dim3(118, 8),  256, 0, stream>>>(x, Phi, Plo, Part, nq2); break;
        case 4:  k_gemm1<4> <<<dim3(118, 4),  256, 0, stream>>>(x, Phi, Plo, Part, nq2); break;
        case 2:  k_gemm1<2> <<<dim3(118, 2),  256, 0, stream>>>(x, Phi, Plo, Part, nq2); break;
        default: k_gemm1<1> <<<dim3(118, 1),  256, 0, stream>>>(x, Phi, Plo, Part, nq2); break;
    }
    k_reduce1<<<826, 256, 0, stream>>>(Part, Sred, nks);
    k_argmax <<<30, 256, 0, stream>>>(Sred, nq2, label, coef, invq, rcnt, rlist);
    k_refine <<<512, 64, 0, stream>>>(x, Sred, invq, label, coef, rcnt, rlist);
    k_lists  <<<30, 256, 0, stream>>>(label, ccnt, clist);
    k_adapt  <<<dim3(8, NCLS, 4), 128, 0, stream>>>(x, coef, ccnt, clist, APpart);
    k_ap1    <<<dim3(NCLS, 4), 256, 0, stream>>>(APpart, proto, es, norm2b);
    k_ap2    <<<dim3(NPAD, 4), 256, 0, stream>>>(APpart, norm2b, APhi);
    switch (nks) {
        case 16: k_gemm2<16><<<dim3(118, 16), 256, 0, stream>>>(x, APhi, Part); break;
        case 8:  k_gemm2<8> <<<dim3(118, 8),  256, 0, stream>>>(x, APhi, Part); break;
        case 4:  k_gemm2<4> <<<dim3(118, 4),  256, 0, stream>>>(x, APhi, Part); break;
        case 2:  k_gemm2<2> <<<dim3(118, 2),  256, 0, stream>>>(x, APhi, Part); break;
        default: k_gemm2<1> <<<dim3(118, 1),  256, 0, stream>>>(x, APhi, Part); break;
    }
    k_reduce2<<<733, 256, 0, stream>>>(Part, invq, tao, (float*)d_out, nks);
}

// Round 5
// 360.521 us; speedup vs baseline: 1.5857x; 1.5857x over previous
//
#include <hip/hip_runtime.h>
#include <hip/hip_bf16.h>
#include <math.h>

// Problem constants (fixed dataset: n=100, k=5, q=75, d=4096)
#define NQUERY 7500
#define NCLS   100
#define DIM    4096
#define KQ     75
#define KSUP   5
#define RPC    80        // rows per class in x = k+q
#define MPAD   7552      // 472 m-tiles * 16
#define NPAD   112       // 7 n-tiles * 16
#define CAPQ   256
#define RCAP   2048
#define EPSF   1e-8f
#define SELEM  845824    // MPAD * NPAD
#define SLICE_BYTES 3383296u

typedef __attribute__((ext_vector_type(8))) short bf16x8;
typedef __attribute__((ext_vector_type(4))) float f32x4;

__device__ __forceinline__ int xrow_of_query(int j) {
    return (j / KQ) * RPC + KSUP + (j % KQ);
}
__device__ __forceinline__ short bf16t(float x) {       // truncate fp32 -> bf16 bits
    union { float f; unsigned u; } v; v.f = x;
    return (short)(v.u >> 16);
}
__device__ __forceinline__ float bf16hi(float x) {      // fp32 with low mantissa cleared
    union { float f; unsigned u; } v; v.f = x;
    v.u &= 0xFFFF0000u; return v.f;
}
// async global->LDS, 16 B per lane: dst gets base+lane*16, src is per-lane addr
__device__ __forceinline__ void gload_lds16(const short* g, short* l) {
    __builtin_amdgcn_global_load_lds(
        (const __attribute__((address_space(1))) unsigned int*)g,
        (__attribute__((address_space(3))) unsigned int*)l, 16, 0, 0);
}

// ---------------- K1a: proto chunk + partial norm2  (grid: NCLS x 4 chunks)
__global__ __launch_bounds__(256) void k_proto1(const float* __restrict__ x,
        float* __restrict__ proto, float* __restrict__ norm2) {
    const int c = blockIdx.x, ch = blockIdx.y, t = threadIdx.x;
    const int i = ch * 1024 + t * 4;
    const float* b0 = x + (size_t)(c * RPC) * DIM;
    f32x4 s = {0.f, 0.f, 0.f, 0.f};
#pragma unroll
    for (int r = 0; r < KSUP; ++r)
        s += *(const f32x4*)(b0 + (size_t)r * DIM + i);
    s = s / 5.0f;
    *(f32x4*)(proto + (size_t)c*DIM + i) = s;
    float ssq = s[0]*s[0] + s[1]*s[1] + s[2]*s[2] + s[3]*s[3];
    for (int o = 32; o; o >>= 1) ssq += __shfl_down(ssq, o);
    if ((t & 63) == 0) atomicAdd(&norm2[c], ssq);
}

// ---------------- K1b: normalize -> Phi/Plo in MFMA tile layout [nt][kstep][kq][lm][8]
// grid NPAD blocks, one class-column each
__global__ __launch_bounds__(256) void k_proto2(const float* __restrict__ proto,
        const float* __restrict__ norm2, short* __restrict__ Phi, short* __restrict__ Plo,
        float* __restrict__ es) {
    const int c = blockIdx.x, t = threadIdx.x;
    const int nt = c >> 4, lm = c & 15;
    if (c >= NCLS) {
        for (int g = t; g < 512; g += 256) {
            const int kstep = g >> 2, kq = g & 3;
            size_t o = (((size_t)(nt * 128 + kstep) * 4 + kq) * 16 + lm) * 8;
            bf16x8 z = {0,0,0,0,0,0,0,0};
            *(bf16x8*)(Phi + o) = z;
            *(bf16x8*)(Plo + o) = z;
        }
        return;
    }
    const float tot = norm2[c];
    const float inv = 1.f / fmaxf(sqrtf(tot), EPSF);
    if (t == 0) es[c] = expf(tot * inv * inv);
    for (int g = t; g < 512; g += 256) {
        const int kstep = g >> 2, kq = g & 3;
        const float* src = proto + (size_t)c * DIM + kstep * 32 + kq * 8;
        f32x4 a = *(const f32x4*)src, b = *(const f32x4*)(src + 4);
        float fv[8] = {a[0],a[1],a[2],a[3],b[0],b[1],b[2],b[3]};
        bf16x8 h, l;
#pragma unroll
        for (int e = 0; e < 8; ++e) {
            float pn = fv[e] * inv;
            float hh = bf16hi(pn);
            h[e] = bf16t(pn);
            l[e] = bf16t(pn - hh);
        }
        size_t o = (((size_t)(nt * 128 + kstep) * 4 + kq) * 16 + lm) * 8;
        *(bf16x8*)(Phi + o) = h;
        *(bf16x8*)(Plo + o) = l;
    }
}

// ---------------- K2: GEMM1 partials, B via LDS (global_load_lds), A direct fp32
// grid (118, TNKS), block 256 = 4 waves, each wave one 16-row m-tile, all 7 n-tiles
template<int TNKS>
__global__ __launch_bounds__(256) void k_gemm1(const float* __restrict__ x,
        const short* __restrict__ Phi, const short* __restrict__ Plo,
        float* __restrict__ Spart, float* __restrict__ nq2) {
    constexpr int KST = 128 / TNKS;   // ksteps (of 32) per block
    constexpr int NG  = KST / 2;      // groups of 2 ksteps
    __shared__ short bbuf[28 * 512];  // 28 chunks x 1KB  [s][nt][hl]
    const int bx = blockIdx.x, kz = blockIdx.y;
    const int w = threadIdx.x >> 6, lane = threadIdx.x & 63;
    const int lm = lane & 15, kq = lane >> 4;
    const int mt = bx * 4 + w;
    const int j = mt * 16 + lm;
    const int jc = j < NQUERY ? j : NQUERY - 1;
    const float* pa = x + (size_t)xrow_of_query(jc) * DIM + kq * 8;
    const int ks0 = kz * KST;

    f32x4 acc[7];
#pragma unroll
    for (int nt = 0; nt < 7; ++nt) acc[nt] = (f32x4){0.f,0.f,0.f,0.f};
    float ssq = 0.f;

    for (int g = 0; g < NG; ++g) {
        const int gk = ks0 + g * 2;
        // stage: wave w stages chunks w*7 .. w*7+6
#pragma unroll
        for (int p = 0; p < 7; ++p) {
            const int cid = w * 7 + p;
            const int s = cid / 14, r = cid % 14, nt = r >> 1, hl = r & 1;
            const short* gsrc = (hl ? Plo : Phi) + ((size_t)(nt * 128 + gk + s) << 9);
            gload_lds16(gsrc + lane * 8, &bbuf[(cid << 9) + lane * 8]);
        }
        __syncthreads();
#pragma unroll
        for (int s = 0; s < 2; ++s) {
            const float* pas = pa + (gk + s) * 32;
            f32x4 f0 = *(const f32x4*)(pas);
            f32x4 f1 = *(const f32x4*)(pas + 4);
            float fv[8] = {f0[0],f0[1],f0[2],f0[3],f1[0],f1[1],f1[2],f1[3]};
            bf16x8 ah, al;
#pragma unroll
            for (int e = 0; e < 8; ++e) {
                float xx = fv[e];
                ssq += xx * xx;
                float hh = bf16hi(xx);
                ah[e] = bf16t(xx);
                al[e] = bf16t(xx - hh);
            }
#pragma unroll
            for (int nt = 0; nt < 7; ++nt) {
                const bf16x8 bh = *(const bf16x8*)(&bbuf[((s*14 + nt*2 + 0) << 9) + lane * 8]);
                const bf16x8 bl = *(const bf16x8*)(&bbuf[((s*14 + nt*2 + 1) << 9) + lane * 8]);
                acc[nt] = __builtin_amdgcn_mfma_f32_16x16x32_bf16(ah, bh, acc[nt], 0, 0, 0);
                acc[nt] = __builtin_amdgcn_mfma_f32_16x16x32_bf16(ah, bl, acc[nt], 0, 0, 0);
                acc[nt] = __builtin_amdgcn_mfma_f32_16x16x32_bf16(al, bh, acc[nt], 0, 0, 0);
            }
        }
        __syncthreads();
    }
    float s2 = ssq;
    s2 += __shfl_xor(s2, 16);
    s2 += __shfl_xor(s2, 32);
    if (kq == 0 && j < NQUERY) atomicAdd(&nq2[j], s2);

    float* sp = Spart + (size_t)kz * SELEM + (size_t)(mt * 16) * NPAD;
#pragma unroll
    for (int nt = 0; nt < 7; ++nt)
#pragma unroll
        for (int r = 0; r < 4; ++r)
            sp[(size_t)(kq * 4 + r) * NPAD + nt * 16 + lm] = acc[nt][r];
}

// ---------------- K2b: Sred = sum over kz slices
__global__ __launch_bounds__(256) void k_reduce1(const float* __restrict__ Spart,
        float* __restrict__ Sred, int nks) {
    const int idx = blockIdx.x * 256 + threadIdx.x;   // < 211456
    const size_t e = (size_t)idx * 4;
    f32x4 s = {0.f, 0.f, 0.f, 0.f};
    for (int kz = 0; kz < nks; ++kz)
        s += *(const f32x4*)(Spart + (size_t)kz * SELEM + e);
    *(f32x4*)(Sred + e) = s;
}

// ---------------- K3: per-query argmax/top2, invq, coef, refine-list
__global__ __launch_bounds__(256) void k_argmax(const float* __restrict__ S,
        const float* __restrict__ nq2, int* __restrict__ label, float* __restrict__ coef,
        float* __restrict__ invq, int* __restrict__ rcnt, int* __restrict__ rlist) {
    const int j = blockIdx.x * 256 + threadIdx.x;
    if (j >= NQUERY) return;
    const float* row = S + (size_t)j * NPAD;
    float m1 = -1e30f, m2 = -1e30f;
    int i1 = 0, i2 = 0;
    for (int c = 0; c < NCLS; ++c) {
        float v = row[c];
        if (v > m1) { m2 = m1; i2 = i1; m1 = v; i1 = c; }
        else if (v > m2) { m2 = v; i2 = c; }
    }
    const float inv = 1.f / fmaxf(sqrtf(nq2[j]), EPSF);
    invq[j] = inv;
    label[j] = i1;
    coef[j] = expf(m1 * inv);
    if ((m1 - m2) * inv < 1e-4f) {
        int p = atomicAdd(rcnt, 1);
        if (p < RCAP) rlist[p] = j | (i1 << 13) | (i2 << 20);
    }
}

// ---------------- K4: fp64 refinement of borderline argmax decisions
__global__ __launch_bounds__(64) void k_refine(const float* __restrict__ x,
        const float* __restrict__ S, const float* __restrict__ invq,
        int* __restrict__ label, float* __restrict__ coef,
        const int* __restrict__ rcnt, const int* __restrict__ rlist) {
    const int cnt = min(*rcnt, RCAP);
    const int lane = threadIdx.x;
    for (int e = blockIdx.x; e < cnt; e += gridDim.x) {
        const int pk = rlist[e];
        const int j = pk & 8191, c1 = (pk >> 13) & 127, c2 = (pk >> 20) & 127;
        const float* xq = x + (size_t)xrow_of_query(j) * DIM;
        const int cc[2] = {c1, c2};
        double cosv[2];
#pragma unroll
        for (int s = 0; s < 2; ++s) {
            const float* xb = x + (size_t)(cc[s] * RPC) * DIM;
            double dt = 0.0, pp = 0.0, q2 = 0.0;
            for (int i = lane; i < DIM; i += 64) {
                double p = (double)xb[i] + (double)xb[i + DIM] + (double)xb[i + 2*DIM]
                         + (double)xb[i + 3*DIM] + (double)xb[i + 4*DIM];
                double qv = (double)xq[i];
                dt += p * qv; pp += p * p; q2 += qv * qv;
            }
            for (int o = 32; o; o >>= 1) {
                dt += __shfl_down(dt, o);
                pp += __shfl_down(pp, o);
                q2 += __shfl_down(q2, o);
            }
            cosv[s] = dt / (sqrt(pp) * sqrt(q2));
        }
        if (lane == 0) {
            int win = (cosv[1] > cosv[0] || (cosv[1] == cosv[0] && c2 < c1)) ? c2 : c1;
            if (win != c1) {
                label[j] = win;
                coef[j] = expf(S[(size_t)j * NPAD + win] * invq[j]);
            }
        }
    }
}

// ---------------- K5: build per-class query lists
__global__ __launch_bounds__(256) void k_lists(const int* __restrict__ label,
        int* __restrict__ cls_cnt, int* __restrict__ cls_list) {
    const int j = blockIdx.x * 256 + threadIdx.x;
    if (j >= NQUERY) return;
    const int c = label[j];
    const int p = atomicAdd(&cls_cnt[c], 1);
    if (p < CAPQ) cls_list[c * CAPQ + p] = j;
}

// ---------------- K6: adapted-proto partial scatter sum (grid 8 x NCLS x 4)
__global__ __launch_bounds__(128) void k_adapt(const float* __restrict__ x,
        const float* __restrict__ coef, const int* __restrict__ cls_cnt,
        const int* __restrict__ cls_list, float* __restrict__ APpart) {
    const int cx = blockIdx.x, c = blockIdx.y, sl = blockIdx.z;
    const int i0 = cx * 512 + threadIdx.x * 4;
    const int n = min(cls_cnt[c], CAPQ);
    f32x4 acc = {0.f, 0.f, 0.f, 0.f};
    for (int e = sl; e < n; e += 4) {
        const int j = cls_list[c * CAPQ + e];
        const float cf = coef[j];
        const f32x4 v = *(const f32x4*)(x + (size_t)xrow_of_query(j) * DIM + i0);
        acc += v * cf;
    }
    *(f32x4*)(APpart + (size_t)sl * NCLS * DIM + (size_t)c * DIM + i0) = acc;
}

// ---------------- K7a: combine slices + es*proto -> APpart slice0, partial norm2b
__global__ __launch_bounds__(256) void k_ap1(float* __restrict__ APpart,
        const float* __restrict__ proto, const float* __restrict__ es,
        float* __restrict__ norm2b) {
    const int c = blockIdx.x, ch = blockIdx.y, t = threadIdx.x;
    const int i = ch * 1024 + t * 4;
    const float e = es[c];
    f32x4 s = {0.f, 0.f, 0.f, 0.f};
#pragma unroll
    for (int sl = 0; sl < 4; ++sl)
        s += *(const f32x4*)(APpart + (size_t)sl * NCLS * DIM + (size_t)c * DIM + i);
    f32x4 pr = *(const f32x4*)(proto + (size_t)c*DIM + i);
    s += pr * e;
    *(f32x4*)(APpart + (size_t)c*DIM + i) = s;   // combined -> slice 0
    float ssq = s[0]*s[0] + s[1]*s[1] + s[2]*s[2] + s[3]*s[3];
    for (int o = 32; o; o >>= 1) ssq += __shfl_down(ssq, o);
    if ((t & 63) == 0) atomicAdd(&norm2b[c], ssq);
}

// ---------------- K7b: normalize -> APhi in tile layout (pad cols zero), grid NPAD
__global__ __launch_bounds__(256) void k_ap2(const float* __restrict__ AP0,
        const float* __restrict__ norm2b, short* __restrict__ APhi) {
    const int c = blockIdx.x, t = threadIdx.x;
    const int nt = c >> 4, lm = c & 15;
    if (c >= NCLS) {
        for (int g = t; g < 512; g += 256) {
            const int kstep = g >> 2, kq = g & 3;
            size_t o = (((size_t)(nt * 128 + kstep) * 4 + kq) * 16 + lm) * 8;
            bf16x8 z = {0,0,0,0,0,0,0,0};
            *(bf16x8*)(APhi + o) = z;
        }
        return;
    }
    const float inv = 1.f / fmaxf(sqrtf(norm2b[c]), EPSF);
    for (int g = t; g < 512; g += 256) {
        const int kstep = g >> 2, kq = g & 3;
        const float* src = AP0 + (size_t)c * DIM + kstep * 32 + kq * 8;
        f32x4 a = *(const f32x4*)src, b = *(const f32x4*)(src + 4);
        float fv[8] = {a[0],a[1],a[2],a[3],b[0],b[1],b[2],b[3]};
        bf16x8 h;
#pragma unroll
        for (int e = 0; e < 8; ++e) h[e] = bf16t(fv[e] * inv);
        size_t o = (((size_t)(nt * 128 + kstep) * 4 + kq) * 16 + lm) * 8;
        *(bf16x8*)(APhi + o) = h;
    }
}

// ---------------- K8: GEMM2 partials, B (APhi) via LDS, A direct fp32
template<int TNKS>
__global__ __launch_bounds__(256) void k_gemm2(const float* __restrict__ x,
        const short* __restrict__ APhi, float* __restrict__ Opart) {
    constexpr int KST = 128 / TNKS;
    constexpr int NG  = KST / 2;
    __shared__ short bbuf[14 * 512];  // 14 chunks x 1KB  [s][nt]
    const int bx = blockIdx.x, kz = blockIdx.y;
    const int w = threadIdx.x >> 6, lane = threadIdx.x & 63;
    const int lm = lane & 15, kq = lane >> 4;
    const int mt = bx * 4 + w;
    const int j = mt * 16 + lm;
    const int jc = j < NQUERY ? j : NQUERY - 1;
    const float* pa = x + (size_t)xrow_of_query(jc) * DIM + kq * 8;
    const int ks0 = kz * KST;

    f32x4 acc[7];
#pragma unroll
    for (int nt = 0; nt < 7; ++nt) acc[nt] = (f32x4){0.f,0.f,0.f,0.f};

    for (int g = 0; g < NG; ++g) {
        const int gk = ks0 + g * 2;
#pragma unroll
        for (int p = 0; p < 4; ++p) {
            const int cid = w * 4 + p;
            if (cid < 14) {
                const int s = cid / 7, nt = cid % 7;
                const short* gsrc = APhi + ((size_t)(nt * 128 + gk + s) << 9);
                gload_lds16(gsrc + lane * 8, &bbuf[(cid << 9) + lane * 8]);
            }
        }
        __syncthreads();
#pragma unroll
        for (int s = 0; s < 2; ++s) {
            const float* pas = pa + (gk + s) * 32;
            f32x4 f0 = *(const f32x4*)(pas);
            f32x4 f1 = *(const f32x4*)(pas + 4);
            float fv[8] = {f0[0],f0[1],f0[2],f0[3],f1[0],f1[1],f1[2],f1[3]};
            bf16x8 ah;
#pragma unroll
            for (int e = 0; e < 8; ++e) ah[e] = bf16t(fv[e]);
#pragma unroll
            for (int nt = 0; nt < 7; ++nt) {
                const bf16x8 bh = *(const bf16x8*)(&bbuf[((s*7 + nt) << 9) + lane * 8]);
                acc[nt] = __builtin_amdgcn_mfma_f32_16x16x32_bf16(ah, bh, acc[nt], 0, 0, 0);
            }
        }
        __syncthreads();
    }
    float* op = Opart + (size_t)kz * SELEM + (size_t)(mt * 16) * NPAD;
#pragma unroll
    for (int nt = 0; nt < 7; ++nt)
#pragma unroll
        for (int r = 0; r < 4; ++r)
            op[(size_t)(kq * 4 + r) * NPAD + nt * 16 + lm] = acc[nt][r];
}

// ---------------- K8b: out[j,c<100] = tao * invq[j] * sum_kz Opart
__global__ __launch_bounds__(256) void k_reduce2(const float* __restrict__ Opart,
        const float* __restrict__ invq, const float* __restrict__ tao,
        float* __restrict__ out, int nks) {
    const int idx = blockIdx.x * 256 + threadIdx.x;   // < 187500
    if (idx >= NQUERY * 25) return;
    const int j = idx / 25, c4 = (idx % 25) * 4;
    const size_t e = (size_t)j * NPAD + c4;
    f32x4 s = {0.f, 0.f, 0.f, 0.f};
    for (int kz = 0; kz < nks; ++kz)
        s += *(const f32x4*)(Opart + (size_t)kz * SELEM + e);
    const float sc = tao[0] * invq[j];
    *(f32x4*)(out + (size_t)j * NCLS + c4) = s * sc;
}

// ---------------- workspace layout (bytes)
#define OFF_RCNT   0u
#define OFF_CCNT   256u
#define OFF_N2     768u
#define OFF_N2B    1280u
#define OFF_NQ2    1792u        // 30000
#define ZERO_BYTES 32768u
#define OFF_ES     32768u
#define OFF_INVQ   33280u
#define OFF_LABEL  63488u
#define OFF_COEF   93696u
#define OFF_RLIST  123904u
#define OFF_CLIST  132096u      // 102400
#define OFF_PROTO  234496u      // 1,638,400
#define OFF_PHI    1872896u     // 917,504 (tile layout)
#define OFF_PLO    2790400u     // 917,504
#define OFF_APHI   3707904u     // 917,504
#define OFF_SRED   4625408u     // 3,383,296
#define OFF_APPART 8008704u     // 4 x 1,638,400
#define OFF_PART   14562304u    // + nks x 3,383,296

extern "C" void kernel_launch(void* const* d_in, const int* in_sizes, int n_in,
                              void* d_out, int out_size, void* d_ws, size_t ws_size,
                              hipStream_t stream) {
    const float* x   = (const float*)d_in[0];
    const float* tao = (const float*)d_in[1];
    char* ws = (char*)d_ws;

    int*   rcnt    = (int*)  (ws + OFF_RCNT);
    int*   ccnt    = (int*)  (ws + OFF_CCNT);
    float* norm2   = (float*)(ws + OFF_N2);
    float* norm2b  = (float*)(ws + OFF_N2B);
    float* nq2     = (float*)(ws + OFF_NQ2);
    float* es      = (float*)(ws + OFF_ES);
    float* invq    = (float*)(ws + OFF_INVQ);
    int*   label   = (int*)  (ws + OFF_LABEL);
    float* coef    = (float*)(ws + OFF_COEF);
    int*   rlist   = (int*)  (ws + OFF_RLIST);
    int*   clist   = (int*)  (ws + OFF_CLIST);
    float* proto   = (float*)(ws + OFF_PROTO);
    short* Phi     = (short*)(ws + OFF_PHI);
    short* Plo     = (short*)(ws + OFF_PLO);
    short* APhi    = (short*)(ws + OFF_APHI);
    float* Sred    = (float*)(ws + OFF_SRED);
    float* APpart  = (float*)(ws + OFF_APPART);
    float* Part    = (float*)(ws + OFF_PART);

    // runtime k-split count from available scratch (pow2, 1..8)
    int nks = 1;
    if (ws_size > (size_t)OFF_PART + SLICE_BYTES) {
        size_t avail = (ws_size - OFF_PART) / SLICE_BYTES;
        nks = avail >= 8 ? 8 : (int)avail;
        while (nks & (nks - 1)) nks &= nks - 1;
    }

    hipMemsetAsync(ws, 0, ZERO_BYTES, stream);

    k_proto1 <<<dim3(NCLS, 4), 256, 0, stream>>>(x, proto, norm2);
    k_proto2 <<<NPAD, 256, 0, stream>>>(proto, norm2, Phi, Plo, es);

    switch (nks) {
        case 8:  k_gemm1<8> <<<dim3(118, 8), 256, 0, stream>>>(x, Phi, Plo, Part, nq2); break;
        case 4:  k_gemm1<4> <<<dim3(118, 4), 256, 0, stream>>>(x, Phi, Plo, Part, nq2); break;
        case 2:  k_gemm1<2> <<<dim3(118, 2), 256, 0, stream>>>(x, Phi, Plo, Part, nq2); break;
        default: k_gemm1<1> <<<dim3(118, 1), 256, 0, stream>>>(x, Phi, Plo, Part, nq2); break;
    }
    k_reduce1<<<826, 256, 0, stream>>>(Part, Sred, nks);
    k_argmax <<<30, 256, 0, stream>>>(Sred, nq2, label, coef, invq, rcnt, rlist);
    k_refine <<<512, 64, 0, stream>>>(x, Sred, invq, label, coef, rcnt, rlist);
    k_lists  <<<30, 256, 0, stream>>>(label, ccnt, clist);
    k_adapt  <<<dim3(8, NCLS, 4), 128, 0, stream>>>(x, coef, ccnt, clist, APpart);
    k_ap1    <<<dim3(NCLS, 4), 256, 0, stream>>>(APpart, proto, es, norm2b);
    k_ap2    <<<NPAD, 256, 0, stream>>>(APpart, norm2b, APhi);
    switch (nks) {
        case 8:  k_gemm2<8> <<<dim3(118, 8), 256, 0, stream>>>(x, APhi, Part); break;
        case 4:  k_gemm2<4> <<<dim3(118, 4), 256, 0, stream>>>(x, APhi, Part); break;
        case 2:  k_gemm2<2> <<<dim3(118, 2), 256, 0, stream>>>(x, APhi, Part); break;
        default: k_gemm2<1> <<<dim3(118, 1), 256, 0, stream>>>(x, APhi, Part); break;
    }
    k_reduce2<<<733, 256, 0, stream>>>(Part, invq, tao, (float*)d_out, nks);
}